// Round 3
// baseline (561.036 us; speedup 1.0000x reference)
//
#include <hip/hip_runtime.h>
#include <hip/hip_bf16.h>

#define BB 8
#define CC 128
#define HH 96
#define WW 96
#define HWH (HH*WW)   // 9216
#define NH 2
#define NP 8
#define HD 64
#define NO 16         // NH*NP

// ---------------- K0: weight prep ----------------
// wt2[c][k][o] from attn_w[o][c][k]  (16x128x9 -> 128x9x16)
// pwT[ci][co]  from proj_w[co][ci]   (128x128)
__global__ __launch_bounds__(256) void prep_w_kernel(
    const float* __restrict__ aw, const float* __restrict__ pw,
    float* __restrict__ wt2, float* __restrict__ pwT) {
  int t = blockIdx.x * 256 + threadIdx.x;
  for (int idx = t; idx < 128 * 9 * 16; idx += gridDim.x * 256) {
    int o = idx & 15;
    int rest = idx >> 4;
    int k = rest % 9;
    int c = rest / 9;
    wt2[idx] = aw[o * 1152 + c * 9 + k];
  }
  for (int idx = t; idx < 128 * 128; idx += gridDim.x * 256) {
    int co = idx & 127;
    int ci = idx >> 7;
    pwT[ci * 128 + co] = pw[co * 128 + ci];
  }
}

// ---------------- K1: value transpose to channel-last bf16 ----------------
// value[b][c][h][w] f32 -> val_t[(b*NH+n)*HWH + pix][d] bf16 , c = n*64+d
__global__ __launch_bounds__(256) void transpose_val_kernel(
    const float* __restrict__ value, __hip_bfloat16* __restrict__ val_t) {
  __shared__ float tile[64][65];
  int blk = blockIdx.x;
  int ptile = blk % (HWH / 64);     // 144
  int bn = blk / (HWH / 64);        // 0..15
  int b = bn >> 1, n = bn & 1;
  int pix0 = ptile * 64;
  int t = threadIdx.x;
  int lane = t & 63;
  int row4 = t >> 6;  // 0..3

  const float* src = value + ((size_t)(b * CC + n * 64)) * HWH + pix0;
#pragma unroll
  for (int i = 0; i < 16; ++i) {
    int c = i * 4 + row4;
    tile[c][lane] = src[(size_t)c * HWH + lane];
  }
  __syncthreads();

  __hip_bfloat16* dst = val_t + ((size_t)bn * HWH + pix0) * 64;
  int d2 = t & 31;   // channel pair index
  int ph = t >> 5;   // 0..7
#pragma unroll
  for (int i = 0; i < 8; ++i) {
    int p = i * 8 + ph;
    __hip_bfloat162 v;
    v.x = __float2bfloat16(tile[d2 * 2][p]);
    v.y = __float2bfloat16(tile[d2 * 2 + 1][p]);
    *reinterpret_cast<__hip_bfloat162*>(dst + (size_t)p * 64 + d2 * 2) = v;
  }
}

// ---------------- K2: 3x3 conv (128->16) + per-head softmax ----------------
// Round-1 structure (1 thread = 1 pixel, 256-px blocks) + unroll-8 channel
// loop for ~72 loads in flight (covers cold-HBM latency at 1 wave/SIMD).
__global__ __launch_bounds__(256) void attn_conv_kernel(
    const float* __restrict__ q, const float* __restrict__ wt2,
    const float* __restrict__ bias, float* __restrict__ attn_out) {
  int gid = blockIdx.x * 256 + threadIdx.x;  // 0..73727 (B*HWH)
  int pix = gid % HWH;
  int b = gid / HWH;
  int h = pix / WW, w = pix % WW;

  float acc[16];
#pragma unroll
  for (int o = 0; o < 16; ++o) acc[o] = bias[o];

  const float* qb = q + (size_t)b * CC * HWH;
  bool hm = h > 0, hp = h < HH - 1, wm = w > 0, wp = w < WW - 1;

#pragma unroll 8
  for (int c = 0; c < 128; ++c) {
    const float* qc = qb + (size_t)c * HWH + pix;
    float qv[9];
    qv[0] = (hm && wm) ? qc[-WW - 1] : 0.f;
    qv[1] = hm ? qc[-WW] : 0.f;
    qv[2] = (hm && wp) ? qc[-WW + 1] : 0.f;
    qv[3] = wm ? qc[-1] : 0.f;
    qv[4] = qc[0];
    qv[5] = wp ? qc[1] : 0.f;
    qv[6] = (hp && wm) ? qc[WW - 1] : 0.f;
    qv[7] = hp ? qc[WW] : 0.f;
    qv[8] = (hp && wp) ? qc[WW + 1] : 0.f;
    const float* wc = wt2 + c * 144;
#pragma unroll
    for (int k = 0; k < 9; ++k) {
#pragma unroll
      for (int o = 0; o < 16; ++o) acc[o] = fmaf(qv[k], wc[k * 16 + o], acc[o]);
    }
  }

  float out[16];
#pragma unroll
  for (int n = 0; n < 2; ++n) {
    float m = acc[n * 8];
#pragma unroll
    for (int p = 1; p < 8; ++p) m = fmaxf(m, acc[n * 8 + p]);
    float s = 0.f;
#pragma unroll
    for (int p = 0; p < 8; ++p) {
      float e = __expf(acc[n * 8 + p] - m);
      out[n * 8 + p] = e;
      s += e;
    }
    float inv = 1.f / s;
#pragma unroll
    for (int p = 0; p < 8; ++p) out[n * 8 + p] *= inv;
  }

  float4* dst = reinterpret_cast<float4*>(attn_out + (size_t)gid * 16);
#pragma unroll
  for (int i = 0; i < 4; ++i)
    dst[i] = make_float4(out[i * 4], out[i * 4 + 1], out[i * 4 + 2], out[i * 4 + 3]);
}

// ---------------- K3: bilinear sampling + point-weighted sum ----------------
// one wave per (b, n, pix); lane = channel d; writes bf16 weighted[pix][c]
__global__ __launch_bounds__(256) void sample_kernel(
    const __hip_bfloat16* __restrict__ val_t, const float* __restrict__ attn,
    const float* __restrict__ refp, __hip_bfloat16* __restrict__ weighted) {
  int t = threadIdx.x;
  int lane = t & 63;
  int wid = __builtin_amdgcn_readfirstlane(blockIdx.x * 4 + (t >> 6));
  int bn = wid / HWH;       // 0..15
  int pix = wid % HWH;
  int b = bn >> 1, n = bn & 1;

  const float* ap = attn + (size_t)(b * HWH + pix) * 16 + n * 8;       // 8 uniform floats
  const float* rp = refp + ((size_t)(b * HWH + pix) * NH + n) * 16;    // 16 uniform floats
  const __hip_bfloat16* vb = val_t + (size_t)bn * HWH * 64;

  float acc = 0.f;
#pragma unroll
  for (int p = 0; p < 8; ++p) {
    float a = ap[p];
    float x = rp[p * 2 + 0] * (float)WW - 0.5f;
    float y = rp[p * 2 + 1] * (float)HH - 0.5f;
    float x0f = floorf(x), y0f = floorf(y);
    float wx = x - x0f, wy = y - y0f;
    int x0 = (int)x0f, y0 = (int)y0f;

    float vx0 = (x0 >= 0) ? 1.f : 0.f;
    float vx1 = (x0 < WW - 1) ? 1.f : 0.f;
    float vy0 = (y0 >= 0) ? 1.f : 0.f;
    float vy1 = (y0 < HH - 1) ? 1.f : 0.f;

    int xc0 = max(x0, 0), xc1 = min(x0 + 1, WW - 1);
    int yc0 = max(y0, 0), yc1 = min(y0 + 1, HH - 1);

    float v00 = __bfloat162float(vb[((size_t)yc0 * WW + xc0) * 64 + lane]);
    float v01 = __bfloat162float(vb[((size_t)yc0 * WW + xc1) * 64 + lane]);
    float v10 = __bfloat162float(vb[((size_t)yc1 * WW + xc0) * 64 + lane]);
    float v11 = __bfloat162float(vb[((size_t)yc1 * WW + xc1) * 64 + lane]);

    float w00 = a * (1.f - wy) * (1.f - wx) * vy0 * vx0;
    float w01 = a * (1.f - wy) * wx * vy0 * vx1;
    float w10 = a * wy * (1.f - wx) * vy1 * vx0;
    float w11 = a * wy * wx * vy1 * vx1;

    acc = fmaf(v00, w00, acc);
    acc = fmaf(v01, w01, acc);
    acc = fmaf(v10, w10, acc);
    acc = fmaf(v11, w11, acc);
  }
  weighted[((size_t)b * HWH + pix) * 128 + n * 64 + lane] = __float2bfloat16(acc);
}

// ---------------- K4: 1x1 projection (K=128 GEMM) ----------------
// out[b][co][pix] = pb[co] + sum_ci weighted[b*HWH+pix][ci] * pwT[ci][co]
__global__ __launch_bounds__(256) void proj_kernel(
    const __hip_bfloat16* __restrict__ weighted, const float* __restrict__ pwT,
    const float* __restrict__ pb, float* __restrict__ out) {
  __shared__ float A[64][129];
  int t = threadIdx.x;
  int pix0 = blockIdx.x * 64;  // global pixel id over B*HWH

  const ushort4* src = reinterpret_cast<const ushort4*>(weighted + (size_t)pix0 * 128);
#pragma unroll
  for (int i = 0; i < 8; ++i) {
    int idx = i * 256 + t;        // 0..2047, each = 4 bf16
    ushort4 v = src[idx];
    int row = idx >> 5;           // 32 quads per 128-ch row
    int col = (idx & 31) * 4;
    A[row][col + 0] = __bfloat162float(*reinterpret_cast<__hip_bfloat16*>(&v.x));
    A[row][col + 1] = __bfloat162float(*reinterpret_cast<__hip_bfloat16*>(&v.y));
    A[row][col + 2] = __bfloat162float(*reinterpret_cast<__hip_bfloat16*>(&v.z));
    A[row][col + 3] = __bfloat162float(*reinterpret_cast<__hip_bfloat16*>(&v.w));
  }
  __syncthreads();

  int lane = t & 63;                                      // pixel in tile
  int g = __builtin_amdgcn_readfirstlane(t >> 6);         // co group 0..3

  float acc[32];
  const float* pbg = pb + g * 32;
#pragma unroll
  for (int j = 0; j < 32; ++j) acc[j] = pbg[j];

  const float* pwt_g = pwT + g * 32;
  for (int ci = 0; ci < 128; ++ci) {
    float a = A[lane][ci];
    const float* row = pwt_g + (size_t)ci * 128;
#pragma unroll
    for (int j = 0; j < 32; ++j) acc[j] = fmaf(a, row[j], acc[j]);
  }

  int gp = pix0 + lane;
  int b = gp / HWH;
  int pixl = gp % HWH;
  float* ob = out + ((size_t)b * CC + g * 32) * HWH + pixl;
#pragma unroll
  for (int j = 0; j < 32; ++j) ob[(size_t)j * HWH] = acc[j];
}

extern "C" void kernel_launch(void* const* d_in, const int* in_sizes, int n_in,
                              void* d_out, int out_size, void* d_ws, size_t ws_size,
                              hipStream_t stream) {
  const float* query = (const float*)d_in[0];
  const float* value = (const float*)d_in[1];
  const float* refp  = (const float*)d_in[2];
  const float* aw    = (const float*)d_in[3];
  const float* ab    = (const float*)d_in[4];
  const float* pw    = (const float*)d_in[5];
  const float* pb    = (const float*)d_in[6];
  float* out = (float*)d_out;

  char* ws = (char*)d_ws;
  float* wt2            = (float*)(ws);                       //   73728 B
  float* pwT            = (float*)(ws + 73728);               //   65536 B
  float* attn_sm        = (float*)(ws + 139264);              // 4718592 B
  __hip_bfloat16* val_t = (__hip_bfloat16*)(ws + 4857856);    // 18874368 B
  __hip_bfloat16* weighted = (__hip_bfloat16*)(ws + 23732224);// 18874368 B
  // total ~42.6 MB

  prep_w_kernel<<<72, 256, 0, stream>>>(aw, pw, wt2, pwT);
  transpose_val_kernel<<<BB * NH * (HWH / 64), 256, 0, stream>>>(value, val_t);
  attn_conv_kernel<<<(BB * HWH) / 256, 256, 0, stream>>>(query, wt2, ab, attn_sm);
  sample_kernel<<<(BB * NH * HWH) / 4, 256, 0, stream>>>(val_t, attn_sm, refp, weighted);
  proj_kernel<<<(BB * HWH) / 64, 256, 0, stream>>>(weighted, pwT, pb, out);
}

// Round 4
// 362.694 us; speedup vs baseline: 1.5469x; 1.5469x over previous
//
#include <hip/hip_runtime.h>
#include <hip/hip_bf16.h>

#define BB 8
#define CC 128
#define HH 96
#define WW 96
#define HWH (HH*WW)   // 9216
#define NH 2
#define NP 8

typedef __attribute__((ext_vector_type(8))) short short8;
typedef __attribute__((ext_vector_type(4))) float f32x4;

// ---------------- K0: weight prep ----------------
// wtb[((k*16 + (c>>3))*16 + o)*8 + (c&7)] = bf16(aw[o][c][k])   (18432 bf16)
// pwT[ci][co] = pw[co][ci]                                       (128x128 f32)
__global__ __launch_bounds__(256) void prep_w_kernel(
    const float* __restrict__ aw, const float* __restrict__ pw,
    __hip_bfloat16* __restrict__ wtb, float* __restrict__ pwT) {
  int t = blockIdx.x * 256 + threadIdx.x;
  for (int idx = t; idx < 9 * 16 * 16 * 8; idx += gridDim.x * 256) {
    int j = idx & 7;
    int o = (idx >> 3) & 15;
    int g = (idx >> 7) & 15;   // c>>3
    int k = idx >> 11;         // 0..8
    int c = g * 8 + j;
    wtb[idx] = __float2bfloat16(aw[o * 1152 + c * 9 + k]);
  }
  for (int idx = t; idx < 128 * 128; idx += gridDim.x * 256) {
    int co = idx & 127;
    int ci = idx >> 7;
    pwT[ci * 128 + co] = pw[co * 128 + ci];
  }
}

// ---------------- K1: value transpose to channel-last bf16 ----------------
__global__ __launch_bounds__(256) void transpose_val_kernel(
    const float* __restrict__ value, __hip_bfloat16* __restrict__ val_t) {
  __shared__ float tile[64][65];
  int blk = blockIdx.x;
  int ptile = blk % (HWH / 64);     // 144
  int bn = blk / (HWH / 64);        // 0..15
  int b = bn >> 1, n = bn & 1;
  int pix0 = ptile * 64;
  int t = threadIdx.x;
  int lane = t & 63;
  int row4 = t >> 6;

  const float* src = value + ((size_t)(b * CC + n * 64)) * HWH + pix0;
#pragma unroll
  for (int i = 0; i < 16; ++i) {
    int c = i * 4 + row4;
    tile[c][lane] = src[(size_t)c * HWH + lane];
  }
  __syncthreads();

  __hip_bfloat16* dst = val_t + ((size_t)bn * HWH + pix0) * 64;
  int d2 = t & 31;
  int ph = t >> 5;
#pragma unroll
  for (int i = 0; i < 8; ++i) {
    int p = i * 8 + ph;
    __hip_bfloat162 v;
    v.x = __float2bfloat16(tile[d2 * 2][p]);
    v.y = __float2bfloat16(tile[d2 * 2 + 1][p]);
    *reinterpret_cast<__hip_bfloat162*>(dst + (size_t)p * 64 + d2 * 2) = v;
  }
}

// ---------------- K2: MFMA conv (128->16, 3x3) + softmax ----------------
// Block = 4 image rows x 96 px (one image row per wave). K = 9 taps x 128 ch,
// chunked 32 channels at a time through a padded bf16 LDS tile [588 px][32 c].
// Padded coords: pad_px = (r+1)*98 + (w+1); tap shift = dy*98+dx (no branches).
__global__ __launch_bounds__(256, 1) void attn_conv_mfma(
    const float* __restrict__ q, const __hip_bfloat16* __restrict__ wtb_,
    const float* __restrict__ bias, float* __restrict__ attn_out) {
  __shared__ char smem[588 * 64];   // 37632 B
  const short* wtb = (const short*)wtb_;
  int t = threadIdx.x;
  int lane = t & 63;
  int wv = t >> 6;                  // wave = image row within tile
  int blk = blockIdx.x;
  int b = blk / 24;
  int rt = blk % 24;
  int h0 = rt * 4;
  const float* qb = q + (size_t)b * CC * HWH;

  float bias_o = bias[lane & 15];
  f32x4 acc[6];
#pragma unroll
  for (int m = 0; m < 6; ++m) acc[m] = (f32x4){bias_o, bias_o, bias_o, bias_o};

  int rowbase = wv * 98 + (lane & 15) + 99;   // padded-coord base for A rows
  int cg16 = (lane >> 4) * 16;                // byte offset of c-group
  const int OFF[9] = {-99, -98, -97, -1, 0, 1, 97, 98, 99};

  for (int ch = 0; ch < 4; ++ch) {
    if (ch) __syncthreads();   // readers done before overwriting LDS
    // ---- stage chunk ch: channels ch*32 + wv*8 .. +7 ----
    int cbase = ch * 32 + wv * 8;
#pragma unroll
    for (int it = 0; it < 10; ++it) {
      int pp = it * 64 + lane;          // padded px 0..587 (+ tail garbage)
      bool vpx = pp < 588;
      int pr = pp / 98;
      int pc = pp - pr * 98;
      int h = h0 + pr - 1;
      int w = pc - 1;
      bool inb = vpx && (h >= 0) && (h < HH) && (w >= 0) && (w < WW);
      int pix = h * WW + w;
      float v[8];
#pragma unroll
      for (int j = 0; j < 8; ++j)
        v[j] = inb ? qb[(size_t)(cbase + j) * HWH + pix] : 0.f;
      uint4 u;
      {
        __hip_bfloat162 p0 = {__float2bfloat16(v[0]), __float2bfloat16(v[1])};
        __hip_bfloat162 p1 = {__float2bfloat16(v[2]), __float2bfloat16(v[3])};
        __hip_bfloat162 p2 = {__float2bfloat16(v[4]), __float2bfloat16(v[5])};
        __hip_bfloat162 p3 = {__float2bfloat16(v[6]), __float2bfloat16(v[7])};
        u.x = *(uint*)&p0; u.y = *(uint*)&p1; u.z = *(uint*)&p2; u.w = *(uint*)&p3;
      }
      if (vpx) {
        int byte = (pp << 6) + (wv << 4);
        byte ^= ((pp >> 1) & 3) << 4;      // write-side swizzle
        *(uint4*)(&smem[byte]) = u;
      }
    }
    __syncthreads();

    // ---- B fragments for this chunk: 9 taps ----
    short8 bf[9];
#pragma unroll
    for (int k = 0; k < 9; ++k) {
      int sidx = ((k * 16 + ch * 4 + (lane >> 4)) * 16 + (lane & 15)) * 8;
      bf[k] = *(const short8*)(wtb + sidx);
    }

    // ---- MFMA: 6 M-tiles x 9 taps ----
#pragma unroll
    for (int m = 0; m < 6; ++m) {
      int base = rowbase + m * 16;
#pragma unroll
      for (int k = 0; k < 9; ++k) {
        int samp = base + OFF[k];
        int byte = (samp << 6) + cg16;
        byte ^= ((samp >> 1) & 3) << 4;    // read-side swizzle (same involution)
        short8 a = *(const short8*)(&smem[byte]);
        acc[m] = __builtin_amdgcn_mfma_f32_16x16x32_bf16(a, bf[k], acc[m], 0, 0, 0);
      }
    }
  }

  // ---- epilogue: softmax over o within each head (o = lane&15, head = o>>3) ----
  int o = lane & 15;
  int rg = lane >> 4;
  size_t gp0 = (size_t)b * HWH + (size_t)(h0 + wv) * 96;
#pragma unroll
  for (int m = 0; m < 6; ++m) {
#pragma unroll
    for (int r = 0; r < 4; ++r) {
      float vv = acc[m][r];
      float mx = vv;
      mx = fmaxf(mx, __shfl_xor(mx, 1, 64));
      mx = fmaxf(mx, __shfl_xor(mx, 2, 64));
      mx = fmaxf(mx, __shfl_xor(mx, 4, 64));
      float e = __expf(vv - mx);
      float s = e;
      s += __shfl_xor(s, 1, 64);
      s += __shfl_xor(s, 2, 64);
      s += __shfl_xor(s, 4, 64);
      float outv = e / s;
      int row = rg * 4 + r;
      attn_out[(gp0 + m * 16 + row) * 16 + o] = outv;
    }
  }
}

// ---------------- K3: bilinear sampling + point-weighted sum ----------------
__global__ __launch_bounds__(256) void sample_kernel(
    const __hip_bfloat16* __restrict__ val_t, const float* __restrict__ attn,
    const float* __restrict__ refp, __hip_bfloat16* __restrict__ weighted) {
  int t = threadIdx.x;
  int lane = t & 63;
  // XCD-aware swizzle: 36864 blocks -> contiguous 4608-block chunk per XCD
  int bid = blockIdx.x;
  int sbid = (bid & 7) * (36864 / 8) + (bid >> 3);
  int wid = __builtin_amdgcn_readfirstlane(sbid * 4 + (t >> 6));
  int bn = wid / HWH;       // 0..15
  int pix = wid % HWH;
  int b = bn >> 1, n = bn & 1;

  const float* ap = attn + (size_t)(b * HWH + pix) * 16 + n * 8;
  const float* rp = refp + ((size_t)(b * HWH + pix) * NH + n) * 16;
  const __hip_bfloat16* vb = val_t + (size_t)bn * HWH * 64;

  float4 a0 = *(const float4*)(ap);
  float4 a1 = *(const float4*)(ap + 4);
  float4 r0 = *(const float4*)(rp);
  float4 r1 = *(const float4*)(rp + 4);
  float4 r2 = *(const float4*)(rp + 8);
  float4 r3 = *(const float4*)(rp + 12);
  float aa[8] = {a0.x, a0.y, a0.z, a0.w, a1.x, a1.y, a1.z, a1.w};
  float rr[16] = {r0.x, r0.y, r0.z, r0.w, r1.x, r1.y, r1.z, r1.w,
                  r2.x, r2.y, r2.z, r2.w, r3.x, r3.y, r3.z, r3.w};

  float acc = 0.f;
#pragma unroll
  for (int p = 0; p < 8; ++p) {
    float a = aa[p];
    float x = rr[p * 2 + 0] * (float)WW - 0.5f;
    float y = rr[p * 2 + 1] * (float)HH - 0.5f;
    float x0f = floorf(x), y0f = floorf(y);
    float wx = x - x0f, wy = y - y0f;
    int x0 = (int)x0f, y0 = (int)y0f;

    float vx0 = (x0 >= 0) ? 1.f : 0.f;
    float vx1 = (x0 < WW - 1) ? 1.f : 0.f;
    float vy0 = (y0 >= 0) ? 1.f : 0.f;
    float vy1 = (y0 < HH - 1) ? 1.f : 0.f;

    int xc0 = max(x0, 0), xc1 = min(x0 + 1, WW - 1);
    int yc0 = max(y0, 0), yc1 = min(y0 + 1, HH - 1);

    float v00 = __bfloat162float(vb[((size_t)yc0 * WW + xc0) * 64 + lane]);
    float v01 = __bfloat162float(vb[((size_t)yc0 * WW + xc1) * 64 + lane]);
    float v10 = __bfloat162float(vb[((size_t)yc1 * WW + xc0) * 64 + lane]);
    float v11 = __bfloat162float(vb[((size_t)yc1 * WW + xc1) * 64 + lane]);

    float w00 = a * (1.f - wy) * (1.f - wx) * vy0 * vx0;
    float w01 = a * (1.f - wy) * wx * vy0 * vx1;
    float w10 = a * wy * (1.f - wx) * vy1 * vx0;
    float w11 = a * wy * wx * vy1 * vx1;

    acc = fmaf(v00, w00, acc);
    acc = fmaf(v01, w01, acc);
    acc = fmaf(v10, w10, acc);
    acc = fmaf(v11, w11, acc);
  }
  weighted[((size_t)b * HWH + pix) * 128 + n * 64 + lane] = __float2bfloat16(acc);
}

// ---------------- K4: 1x1 projection (K=128 GEMM) ----------------
__global__ __launch_bounds__(256) void proj_kernel(
    const __hip_bfloat16* __restrict__ weighted, const float* __restrict__ pwT,
    const float* __restrict__ pb, float* __restrict__ out) {
  __shared__ float A[64][129];
  int t = threadIdx.x;
  int pix0 = blockIdx.x * 64;

  const ushort4* src = reinterpret_cast<const ushort4*>(weighted + (size_t)pix0 * 128);
#pragma unroll
  for (int i = 0; i < 8; ++i) {
    int idx = i * 256 + t;
    ushort4 v = src[idx];
    int row = idx >> 5;
    int col = (idx & 31) * 4;
    A[row][col + 0] = __bfloat162float(*reinterpret_cast<__hip_bfloat16*>(&v.x));
    A[row][col + 1] = __bfloat162float(*reinterpret_cast<__hip_bfloat16*>(&v.y));
    A[row][col + 2] = __bfloat162float(*reinterpret_cast<__hip_bfloat16*>(&v.z));
    A[row][col + 3] = __bfloat162float(*reinterpret_cast<__hip_bfloat16*>(&v.w));
  }
  __syncthreads();

  int lane = t & 63;
  int g = __builtin_amdgcn_readfirstlane(t >> 6);

  float acc[32];
  const float* pbg = pb + g * 32;
#pragma unroll
  for (int j = 0; j < 32; ++j) acc[j] = pbg[j];

  const float* pwt_g = pwT + g * 32;
  for (int ci = 0; ci < 128; ++ci) {
    float a = A[lane][ci];
    const float* row = pwt_g + (size_t)ci * 128;
#pragma unroll
    for (int j = 0; j < 32; ++j) acc[j] = fmaf(a, row[j], acc[j]);
  }

  int gp = pix0 + lane;
  int b = gp / HWH;
  int pixl = gp % HWH;
  float* ob = out + ((size_t)b * CC + g * 32) * HWH + pixl;
#pragma unroll
  for (int j = 0; j < 32; ++j) ob[(size_t)j * HWH] = acc[j];
}

extern "C" void kernel_launch(void* const* d_in, const int* in_sizes, int n_in,
                              void* d_out, int out_size, void* d_ws, size_t ws_size,
                              hipStream_t stream) {
  const float* query = (const float*)d_in[0];
  const float* value = (const float*)d_in[1];
  const float* refp  = (const float*)d_in[2];
  const float* aw    = (const float*)d_in[3];
  const float* ab    = (const float*)d_in[4];
  const float* pw    = (const float*)d_in[5];
  const float* pb    = (const float*)d_in[6];
  float* out = (float*)d_out;

  char* ws = (char*)d_ws;
  __hip_bfloat16* wtb   = (__hip_bfloat16*)(ws);              //   36864 B (pad to 40960)
  float* pwT            = (float*)(ws + 40960);               //   65536 B
  float* attn_sm        = (float*)(ws + 106496);              // 4718592 B
  __hip_bfloat16* val_t = (__hip_bfloat16*)(ws + 4825088);    // 18874368 B
  __hip_bfloat16* weighted = (__hip_bfloat16*)(ws + 23699456);// 18874368 B
  // total ~42.6 MB

  prep_w_kernel<<<72, 256, 0, stream>>>(aw, pw, wtb, pwT);
  transpose_val_kernel<<<BB * NH * (HWH / 64), 256, 0, stream>>>(value, val_t);
  attn_conv_mfma<<<BB * (HH / 4), 256, 0, stream>>>(query, wtb, ab, attn_sm);
  sample_kernel<<<(BB * NH * HWH) / 4, 256, 0, stream>>>(val_t, attn_sm, refp, weighted);
  proj_kernel<<<(BB * HWH) / 64, 256, 0, stream>>>(weighted, pwT, pb, out);
}

// Round 6
// 286.028 us; speedup vs baseline: 1.9615x; 1.2680x over previous
//
#include <hip/hip_runtime.h>
#include <hip/hip_bf16.h>

#define BB 8
#define CC 128
#define HH 96
#define WW 96
#define HWH (HH*WW)   // 9216
#define NH 2
#define NP 8
#define PW 98         // padded width/height
#define PHW (PW*PW)   // 9604

typedef __attribute__((ext_vector_type(8))) short short8;
typedef __attribute__((ext_vector_type(4))) float f32x4;

// ---------------- K0: weight prep ----------------
// wtb[((k*16 + (c>>3))*16 + o)*8 + (c&7)] = bf16(aw[o][c][k])   (18432 bf16)
// pwT[ci][co] = pw[co][ci]                                       (128x128 f32)
__global__ __launch_bounds__(256) void prep_w_kernel(
    const float* __restrict__ aw, const float* __restrict__ pw,
    __hip_bfloat16* __restrict__ wtb, float* __restrict__ pwT) {
  int t = blockIdx.x * 256 + threadIdx.x;
  for (int idx = t; idx < 9 * 16 * 16 * 8; idx += gridDim.x * 256) {
    int j = idx & 7;
    int o = (idx >> 3) & 15;
    int g = (idx >> 7) & 15;   // c>>3
    int k = idx >> 11;         // 0..8
    int c = g * 8 + j;
    wtb[idx] = __float2bfloat16(aw[o * 1152 + c * 9 + k]);
  }
  for (int idx = t; idx < 128 * 128; idx += gridDim.x * 256) {
    int co = idx & 127;
    int ci = idx >> 7;
    pwT[ci * 128 + co] = pw[co * 128 + ci];
  }
}

// ---------------- K1: transpose value AND query to channel-last bf16 ----------
// mode 0 (blk < 2304): value -> val_t[(b*2+n)*HWH + pix][64]
// mode 1 (blk >= 2304): query -> q_pad[b*PHW + (h+1)*98 + (w+1)][128] (interior)
__global__ __launch_bounds__(256) void transpose_cl_kernel(
    const float* __restrict__ value, const float* __restrict__ query,
    __hip_bfloat16* __restrict__ val_t, __hip_bfloat16* __restrict__ q_pad) {
  __shared__ float tile[64][65];
  int blk = blockIdx.x;
  int mode = blk / 2304;
  int r = blk % 2304;
  int ptile = r % 144;
  int bn = r / 144;
  int b = bn >> 1, n = bn & 1;
  int pix0 = ptile * 64;
  int t = threadIdx.x;
  int lane = t & 63;
  int row4 = t >> 6;

  const float* srcp = (mode ? query : value) + ((size_t)(b * CC + n * 64)) * HWH + pix0;
#pragma unroll
  for (int i = 0; i < 16; ++i) {
    int c = i * 4 + row4;
    tile[c][lane] = srcp[(size_t)c * HWH + lane];
  }
  __syncthreads();

  int d2 = t & 31;   // channel pair
  int ph = t >> 5;   // 0..7
  if (mode == 0) {
    __hip_bfloat16* dst = val_t + ((size_t)bn * HWH + pix0) * 64;
#pragma unroll
    for (int i = 0; i < 8; ++i) {
      int p = i * 8 + ph;
      __hip_bfloat162 v;
      v.x = __float2bfloat16(tile[d2 * 2][p]);
      v.y = __float2bfloat16(tile[d2 * 2 + 1][p]);
      *reinterpret_cast<__hip_bfloat162*>(dst + (size_t)p * 64 + d2 * 2) = v;
    }
  } else {
#pragma unroll
    for (int i = 0; i < 8; ++i) {
      int p = i * 8 + ph;
      int gp = pix0 + p;
      int h = gp / WW, w = gp - h * WW;
      __hip_bfloat162 v;
      v.x = __float2bfloat16(tile[d2 * 2][p]);
      v.y = __float2bfloat16(tile[d2 * 2 + 1][p]);
      size_t off = ((size_t)b * PHW + (size_t)(h + 1) * PW + (w + 1)) * 128 + n * 64 + d2 * 2;
      *reinterpret_cast<__hip_bfloat162*>(q_pad + off) = v;
    }
  }
}

// ---------------- K2: MFMA conv (128->16, 3x3) + softmax ----------------
// One wave = one 16-px M-tile (same image row). No LDS, no barriers.
// A-frags loaded directly from zero-padded channel-last q_pad (no predication).
// XCD swizzle: 1152 blocks -> XCD x owns batch x (144 blocks = 576 tiles = 1 b).
__global__ __launch_bounds__(256) void attn_conv_mfma2(
    const __hip_bfloat16* __restrict__ q_pad, const __hip_bfloat16* __restrict__ wtb_,
    const float* __restrict__ bias, float* __restrict__ attn_out) {
  int t = threadIdx.x;
  int l = t & 63;
  int bid = blockIdx.x;
  int sbid = (bid & 7) * 144 + (bid >> 3);
  int tid = __builtin_amdgcn_readfirstlane(sbid * 4 + (t >> 6));  // 0..4607
  int b = tid / 576;
  int rem = tid % 576;
  int h = rem / 6;
  int w0 = (rem % 6) * 16;

  const char* qb = (const char*)q_pad;
  const char* wb = (const char*)wtb_;

  int pxbase = b * PHW + (h + 1) * PW + (w0 + 1);
  int lb  = (l & 15) * 256 + (l >> 4) * 16;   // A lane byte offset (px, ch-part)
  int wlb = (l >> 4) * 256 + (l & 15) * 16;   // B lane byte offset

  float bias_o = bias[l & 15];
  f32x4 acc0 = {bias_o, bias_o, bias_o, bias_o};
  f32x4 acc1 = {0.f, 0.f, 0.f, 0.f};

#pragma unroll
  for (int k = 0; k < 9; ++k) {
    int dy = k / 3 - 1, dx = (k % 3) - 1;
    const char* abase = qb + ((size_t)pxbase + dy * PW + dx) * 256 + lb;
    const char* bbase = wb + k * 4096 + wlb;
#pragma unroll
    for (int c4 = 0; c4 < 4; ++c4) {
      short8 a = *(const short8*)(abase + c4 * 64);
      short8 bf = *(const short8*)(bbase + c4 * 1024);
      if (k & 1)
        acc1 = __builtin_amdgcn_mfma_f32_16x16x32_bf16(a, bf, acc1, 0, 0, 0);
      else
        acc0 = __builtin_amdgcn_mfma_f32_16x16x32_bf16(a, bf, acc0, 0, 0, 0);
    }
  }

  // softmax over o within each head (o = l&15, head = o>>3), px = (l>>4)*4+r
  int o = l & 15;
  size_t row0 = (size_t)b * HWH + (size_t)h * 96 + w0 + (l >> 4) * 4;
#pragma unroll
  for (int r = 0; r < 4; ++r) {
    float vv = acc0[r] + acc1[r];
    float mx = vv;
    mx = fmaxf(mx, __shfl_xor(mx, 1, 64));
    mx = fmaxf(mx, __shfl_xor(mx, 2, 64));
    mx = fmaxf(mx, __shfl_xor(mx, 4, 64));
    float e = __expf(vv - mx);
    float s = e;
    s += __shfl_xor(s, 1, 64);
    s += __shfl_xor(s, 2, 64);
    s += __shfl_xor(s, 4, 64);
    attn_out[(row0 + r) * 16 + o] = e / s;
  }
}

// ---------------- K3: bilinear sampling + point-weighted sum ----------------
__global__ __launch_bounds__(256) void sample_kernel(
    const __hip_bfloat16* __restrict__ val_t, const float* __restrict__ attn,
    const float* __restrict__ refp, __hip_bfloat16* __restrict__ weighted) {
  int t = threadIdx.x;
  int lane = t & 63;
  // XCD-aware swizzle: contiguous 4608-block chunk per XCD
  int bid = blockIdx.x;
  int sbid = (bid & 7) * (36864 / 8) + (bid >> 3);
  int wid = __builtin_amdgcn_readfirstlane(sbid * 4 + (t >> 6));
  int bn = wid / HWH;       // 0..15
  int pix = wid % HWH;
  int b = bn >> 1, n = bn & 1;

  const float* ap = attn + (size_t)(b * HWH + pix) * 16 + n * 8;
  const float* rp = refp + ((size_t)(b * HWH + pix) * NH + n) * 16;
  const __hip_bfloat16* vb = val_t + (size_t)bn * HWH * 64;

  float4 a0 = *(const float4*)(ap);
  float4 a1 = *(const float4*)(ap + 4);
  float4 r0 = *(const float4*)(rp);
  float4 r1 = *(const float4*)(rp + 4);
  float4 r2 = *(const float4*)(rp + 8);
  float4 r3 = *(const float4*)(rp + 12);
  float aa[8] = {a0.x, a0.y, a0.z, a0.w, a1.x, a1.y, a1.z, a1.w};
  float rr[16] = {r0.x, r0.y, r0.z, r0.w, r1.x, r1.y, r1.z, r1.w,
                  r2.x, r2.y, r2.z, r2.w, r3.x, r3.y, r3.z, r3.w};

  float acc = 0.f;
#pragma unroll
  for (int p = 0; p < 8; ++p) {
    float a = aa[p];
    float x = rr[p * 2 + 0] * (float)WW - 0.5f;
    float y = rr[p * 2 + 1] * (float)HH - 0.5f;
    float x0f = floorf(x), y0f = floorf(y);
    float wx = x - x0f, wy = y - y0f;
    int x0 = (int)x0f, y0 = (int)y0f;

    float vx0 = (x0 >= 0) ? 1.f : 0.f;
    float vx1 = (x0 < WW - 1) ? 1.f : 0.f;
    float vy0 = (y0 >= 0) ? 1.f : 0.f;
    float vy1 = (y0 < HH - 1) ? 1.f : 0.f;

    int xc0 = max(x0, 0), xc1 = min(x0 + 1, WW - 1);
    int yc0 = max(y0, 0), yc1 = min(y0 + 1, HH - 1);

    float v00 = __bfloat162float(vb[((size_t)yc0 * WW + xc0) * 64 + lane]);
    float v01 = __bfloat162float(vb[((size_t)yc0 * WW + xc1) * 64 + lane]);
    float v10 = __bfloat162float(vb[((size_t)yc1 * WW + xc0) * 64 + lane]);
    float v11 = __bfloat162float(vb[((size_t)yc1 * WW + xc1) * 64 + lane]);

    float w00 = a * (1.f - wy) * (1.f - wx) * vy0 * vx0;
    float w01 = a * (1.f - wy) * wx * vy0 * vx1;
    float w10 = a * wy * (1.f - wx) * vy1 * vx0;
    float w11 = a * wy * wx * vy1 * vx1;

    acc = fmaf(v00, w00, acc);
    acc = fmaf(v01, w01, acc);
    acc = fmaf(v10, w10, acc);
    acc = fmaf(v11, w11, acc);
  }
  weighted[((size_t)b * HWH + pix) * 128 + n * 64 + lane] = __float2bfloat16(acc);
}

// ---------------- K4: 1x1 projection (K=128 GEMM) ----------------
__global__ __launch_bounds__(256) void proj_kernel(
    const __hip_bfloat16* __restrict__ weighted, const float* __restrict__ pwT,
    const float* __restrict__ pb, float* __restrict__ out) {
  __shared__ float A[64][129];
  int t = threadIdx.x;
  int pix0 = blockIdx.x * 64;

  const ushort4* src = reinterpret_cast<const ushort4*>(weighted + (size_t)pix0 * 128);
#pragma unroll
  for (int i = 0; i < 8; ++i) {
    int idx = i * 256 + t;
    ushort4 v = src[idx];
    int row = idx >> 5;
    int col = (idx & 31) * 4;
    A[row][col + 0] = __bfloat162float(*reinterpret_cast<__hip_bfloat16*>(&v.x));
    A[row][col + 1] = __bfloat162float(*reinterpret_cast<__hip_bfloat16*>(&v.y));
    A[row][col + 2] = __bfloat162float(*reinterpret_cast<__hip_bfloat16*>(&v.z));
    A[row][col + 3] = __bfloat162float(*reinterpret_cast<__hip_bfloat16*>(&v.w));
  }
  __syncthreads();

  int lane = t & 63;
  int g = __builtin_amdgcn_readfirstlane(t >> 6);

  float acc[32];
  const float* pbg = pb + g * 32;
#pragma unroll
  for (int j = 0; j < 32; ++j) acc[j] = pbg[j];

  const float* pwt_g = pwT + g * 32;
  for (int ci = 0; ci < 128; ++ci) {
    float a = A[lane][ci];
    const float* row = pwt_g + (size_t)ci * 128;
#pragma unroll
    for (int j = 0; j < 32; ++j) acc[j] = fmaf(a, row[j], acc[j]);
  }

  int gp = pix0 + lane;
  int b = gp / HWH;
  int pixl = gp % HWH;
  float* ob = out + ((size_t)b * CC + g * 32) * HWH + pixl;
#pragma unroll
  for (int j = 0; j < 32; ++j) ob[(size_t)j * HWH] = acc[j];
}

extern "C" void kernel_launch(void* const* d_in, const int* in_sizes, int n_in,
                              void* d_out, int out_size, void* d_ws, size_t ws_size,
                              hipStream_t stream) {
  const float* query = (const float*)d_in[0];
  const float* value = (const float*)d_in[1];
  const float* refp  = (const float*)d_in[2];
  const float* aw    = (const float*)d_in[3];
  const float* ab    = (const float*)d_in[4];
  const float* pw    = (const float*)d_in[5];
  const float* pb    = (const float*)d_in[6];
  float* out = (float*)d_out;

  // Workspace layout (aliased q_pad/weighted: q_pad dead after conv,
  // weighted first written by sample). Total 43,368,448 B — well under the
  // round-1-proven 61.48 MB budget (round-5 OOB at 62.2 MB caused the
  // post-timing divergence).
  char* ws = (char*)d_ws;
  __hip_bfloat16* wtb      = (__hip_bfloat16*)(ws);             //   36864 B (pad 40960)
  float* pwT               = (float*)(ws + 40960);              //   65536 B
  float* attn_sm           = (float*)(ws + 106496);             // 4718592 B
  __hip_bfloat16* val_t    = (__hip_bfloat16*)(ws + 4825088);   // 18874368 B
  __hip_bfloat16* q_pad    = (__hip_bfloat16*)(ws + 23699456);  // 19668992 B (shared)
  __hip_bfloat16* weighted = (__hip_bfloat16*)(ws + 23699456);  // 18874368 B (shared)
  // end = 43368448 B

  hipMemsetAsync(q_pad, 0, (size_t)BB * PHW * 128 * 2, stream);
  prep_w_kernel<<<72, 256, 0, stream>>>(aw, pw, wtb, pwT);
  transpose_cl_kernel<<<4608, 256, 0, stream>>>(value, query, val_t, q_pad);
  attn_conv_mfma2<<<1152, 256, 0, stream>>>(q_pad, wtb, ab, attn_sm);
  sample_kernel<<<(BB * NH * HWH) / 4, 256, 0, stream>>>(val_t, attn_sm, refp, weighted);
  proj_kernel<<<(BB * HWH) / 64, 256, 0, stream>>>(weighted, pwT, pb, out);
}

// Round 7
// 256.936 us; speedup vs baseline: 2.1836x; 1.1132x over previous
//
#include <hip/hip_runtime.h>
#include <hip/hip_bf16.h>

#define BB 8
#define CC 128
#define HH 96
#define WW 96
#define HWH (HH*WW)   // 9216
#define NH 2
#define NP 8
#define PW 98         // padded width/height
#define PHW (PW*PW)   // 9604

typedef __attribute__((ext_vector_type(8))) short short8;
typedef __attribute__((ext_vector_type(4))) float f32x4;

__device__ __forceinline__ float bf_lo(unsigned u) { return __uint_as_float(u << 16); }
__device__ __forceinline__ float bf_hi(unsigned u) { return __uint_as_float(u & 0xffff0000u); }

// ---------------- K0: weight prep ----------------
// wtb[((k*16 + (c>>3))*16 + o)*8 + (c&7)] = bf16(aw[o][c][k])   (18432 bf16)
// pwT[ci][co] = pw[co][ci]                                       (128x128 f32)
__global__ __launch_bounds__(256) void prep_w_kernel(
    const float* __restrict__ aw, const float* __restrict__ pw,
    __hip_bfloat16* __restrict__ wtb, float* __restrict__ pwT) {
  int t = blockIdx.x * 256 + threadIdx.x;
  for (int idx = t; idx < 9 * 16 * 16 * 8; idx += gridDim.x * 256) {
    int j = idx & 7;
    int o = (idx >> 3) & 15;
    int g = (idx >> 7) & 15;   // c>>3
    int k = idx >> 11;         // 0..8
    int c = g * 8 + j;
    wtb[idx] = __float2bfloat16(aw[o * 1152 + c * 9 + k]);
  }
  for (int idx = t; idx < 128 * 128; idx += gridDim.x * 256) {
    int co = idx & 127;
    int ci = idx >> 7;
    pwT[ci * 128 + co] = pw[co * 128 + ci];
  }
}

// ---------------- K1: transpose value AND query to channel-last bf16 ----------
// mode 0 (blk < 2304): value -> val_t[(b*2+n)*HWH + pix][64]
// mode 1 (blk >= 2304): query -> q_pad[b*PHW + (h+1)*98 + (w+1)][128] (interior)
__global__ __launch_bounds__(256) void transpose_cl_kernel(
    const float* __restrict__ value, const float* __restrict__ query,
    __hip_bfloat16* __restrict__ val_t, __hip_bfloat16* __restrict__ q_pad) {
  __shared__ float tile[64][65];
  int blk = blockIdx.x;
  int mode = blk / 2304;
  int r = blk % 2304;
  int ptile = r % 144;
  int bn = r / 144;
  int b = bn >> 1, n = bn & 1;
  int pix0 = ptile * 64;
  int t = threadIdx.x;
  int lane = t & 63;
  int row4 = t >> 6;

  const float* srcp = (mode ? query : value) + ((size_t)(b * CC + n * 64)) * HWH + pix0;
#pragma unroll
  for (int i = 0; i < 16; ++i) {
    int c = i * 4 + row4;
    tile[c][lane] = srcp[(size_t)c * HWH + lane];
  }
  __syncthreads();

  int d2 = t & 31;   // channel pair
  int ph = t >> 5;   // 0..7
  if (mode == 0) {
    __hip_bfloat16* dst = val_t + ((size_t)bn * HWH + pix0) * 64;
#pragma unroll
    for (int i = 0; i < 8; ++i) {
      int p = i * 8 + ph;
      __hip_bfloat162 v;
      v.x = __float2bfloat16(tile[d2 * 2][p]);
      v.y = __float2bfloat16(tile[d2 * 2 + 1][p]);
      *reinterpret_cast<__hip_bfloat162*>(dst + (size_t)p * 64 + d2 * 2) = v;
    }
  } else {
#pragma unroll
    for (int i = 0; i < 8; ++i) {
      int p = i * 8 + ph;
      int gp = pix0 + p;
      int h = gp / WW, w = gp - h * WW;
      __hip_bfloat162 v;
      v.x = __float2bfloat16(tile[d2 * 2][p]);
      v.y = __float2bfloat16(tile[d2 * 2 + 1][p]);
      size_t off = ((size_t)b * PHW + (size_t)(h + 1) * PW + (w + 1)) * 128 + n * 64 + d2 * 2;
      *reinterpret_cast<__hip_bfloat162*>(q_pad + off) = v;
    }
  }
}

// ---------------- K2: MFMA conv (128->16, 3x3) + softmax ----------------
// One wave = one 16-px M-tile (same image row). No LDS, no barriers.
__global__ __launch_bounds__(256) void attn_conv_mfma2(
    const __hip_bfloat16* __restrict__ q_pad, const __hip_bfloat16* __restrict__ wtb_,
    const float* __restrict__ bias, float* __restrict__ attn_out) {
  int t = threadIdx.x;
  int l = t & 63;
  int bid = blockIdx.x;
  int sbid = (bid & 7) * 144 + (bid >> 3);
  int tid = __builtin_amdgcn_readfirstlane(sbid * 4 + (t >> 6));  // 0..4607
  int b = tid / 576;
  int rem = tid % 576;
  int h = rem / 6;
  int w0 = (rem % 6) * 16;

  const char* qb = (const char*)q_pad;
  const char* wb = (const char*)wtb_;

  int pxbase = b * PHW + (h + 1) * PW + (w0 + 1);
  int lb  = (l & 15) * 256 + (l >> 4) * 16;   // A lane byte offset (px, ch-part)
  int wlb = (l >> 4) * 256 + (l & 15) * 16;   // B lane byte offset

  float bias_o = bias[l & 15];
  f32x4 acc0 = {bias_o, bias_o, bias_o, bias_o};
  f32x4 acc1 = {0.f, 0.f, 0.f, 0.f};

#pragma unroll
  for (int k = 0; k < 9; ++k) {
    int dy = k / 3 - 1, dx = (k % 3) - 1;
    const char* abase = qb + ((size_t)pxbase + dy * PW + dx) * 256 + lb;
    const char* bbase = wb + k * 4096 + wlb;
#pragma unroll
    for (int c4 = 0; c4 < 4; ++c4) {
      short8 a = *(const short8*)(abase + c4 * 64);
      short8 bf = *(const short8*)(bbase + c4 * 1024);
      if (k & 1)
        acc1 = __builtin_amdgcn_mfma_f32_16x16x32_bf16(a, bf, acc1, 0, 0, 0);
      else
        acc0 = __builtin_amdgcn_mfma_f32_16x16x32_bf16(a, bf, acc0, 0, 0, 0);
    }
  }

  // softmax over o within each head (o = l&15, head = o>>3), px = (l>>4)*4+r
  int o = l & 15;
  size_t row0 = (size_t)b * HWH + (size_t)h * 96 + w0 + (l >> 4) * 4;
#pragma unroll
  for (int r = 0; r < 4; ++r) {
    float vv = acc0[r] + acc1[r];
    float mx = vv;
    mx = fmaxf(mx, __shfl_xor(mx, 1, 64));
    mx = fmaxf(mx, __shfl_xor(mx, 2, 64));
    mx = fmaxf(mx, __shfl_xor(mx, 4, 64));
    float e = __expf(vv - mx);
    float s = e;
    s += __shfl_xor(s, 1, 64);
    s += __shfl_xor(s, 2, 64);
    s += __shfl_xor(s, 4, 64);
    attn_out[(row0 + r) * 16 + o] = e / s;
  }
}

// ---------------- K3: bilinear sampling + point-weighted sum ----------------
// 4 pixel-units per wave (16 lanes each, lane = 4 channels via ushort4 load).
// All addressing 32-bit. Each lane computes its own pixel's weight math.
__global__ __launch_bounds__(256) void sample_kernel(
    const __hip_bfloat16* __restrict__ val_t, const float* __restrict__ attn,
    const float* __restrict__ refp, __hip_bfloat16* __restrict__ weighted) {
  int t = threadIdx.x;
  int lane = t & 63;
  int sub = lane >> 4;          // pixel-unit within wave 0..3
  int lq = lane & 15;           // channel group (4 ch each)
  // XCD-aware swizzle: 9216 blocks -> contiguous 1152-block chunk per XCD
  int bid = blockIdx.x;
  int sbid = (bid & 7) * 1152 + (bid >> 3);
  int unit = (sbid * 4 + (t >> 6)) * 4 + sub;   // 0..147455 = (b,n,pix)
  int bn = unit / HWH;
  int pix = unit - bn * HWH;
  int bq = bn >> 1, n = bn & 1;

  const float* ap = attn + ((size_t)bq * HWH + pix) * 16 + n * 8;
  const float* rp = refp + (((size_t)bq * HWH + pix) * NH + n) * 16;
  const __hip_bfloat16* vb = val_t + (size_t)bn * (HWH * 64);

  float4 a0 = *(const float4*)(ap);
  float4 a1 = *(const float4*)(ap + 4);
  float4 r0 = *(const float4*)(rp);
  float4 r1 = *(const float4*)(rp + 4);
  float4 r2 = *(const float4*)(rp + 8);
  float4 r3 = *(const float4*)(rp + 12);
  float aa[8] = {a0.x, a0.y, a0.z, a0.w, a1.x, a1.y, a1.z, a1.w};
  float rr[16] = {r0.x, r0.y, r0.z, r0.w, r1.x, r1.y, r1.z, r1.w,
                  r2.x, r2.y, r2.z, r2.w, r3.x, r3.y, r3.z, r3.w};

  float acc0 = 0.f, acc1 = 0.f, acc2 = 0.f, acc3 = 0.f;
  int lq4 = lq * 4;
#pragma unroll
  for (int p = 0; p < 8; ++p) {
    float a = aa[p];
    float x = rr[p * 2 + 0] * (float)WW - 0.5f;
    float y = rr[p * 2 + 1] * (float)HH - 0.5f;
    float x0f = floorf(x), y0f = floorf(y);
    float wx = x - x0f, wy = y - y0f;
    int x0 = (int)x0f, y0 = (int)y0f;

    // fold validity into row/col weights
    float ay0 = a * (1.f - wy);  ay0 = (y0 >= 0)      ? ay0 : 0.f;
    float ay1 = a * wy;          ay1 = (y0 < HH - 1)  ? ay1 : 0.f;
    float bx0 = 1.f - wx;        bx0 = (x0 >= 0)      ? bx0 : 0.f;
    float bx1 = wx;              bx1 = (x0 < WW - 1)  ? bx1 : 0.f;

    int xc0 = max(x0, 0), xc1 = min(x0 + 1, WW - 1);
    int yc0 = max(y0, 0), yc1 = min(y0 + 1, HH - 1);

    int r0o = yc0 * (WW * 64);
    int r1o = yc1 * (WW * 64);
    int c0o = xc0 * 64 + lq4;
    int c1o = xc1 * 64 + lq4;

    const uint2* p00 = (const uint2*)(vb + (r0o + c0o));
    const uint2* p01 = (const uint2*)(vb + (r0o + c1o));
    const uint2* p10 = (const uint2*)(vb + (r1o + c0o));
    const uint2* p11 = (const uint2*)(vb + (r1o + c1o));
    uint2 u00 = *p00, u01 = *p01, u10 = *p10, u11 = *p11;

    float w00 = ay0 * bx0, w01 = ay0 * bx1, w10 = ay1 * bx0, w11 = ay1 * bx1;

    acc0 = fmaf(bf_lo(u00.x), w00, acc0);
    acc1 = fmaf(bf_hi(u00.x), w00, acc1);
    acc2 = fmaf(bf_lo(u00.y), w00, acc2);
    acc3 = fmaf(bf_hi(u00.y), w00, acc3);

    acc0 = fmaf(bf_lo(u01.x), w01, acc0);
    acc1 = fmaf(bf_hi(u01.x), w01, acc1);
    acc2 = fmaf(bf_lo(u01.y), w01, acc2);
    acc3 = fmaf(bf_hi(u01.y), w01, acc3);

    acc0 = fmaf(bf_lo(u10.x), w10, acc0);
    acc1 = fmaf(bf_hi(u10.x), w10, acc1);
    acc2 = fmaf(bf_lo(u10.y), w10, acc2);
    acc3 = fmaf(bf_hi(u10.y), w10, acc3);

    acc0 = fmaf(bf_lo(u11.x), w11, acc0);
    acc1 = fmaf(bf_hi(u11.x), w11, acc1);
    acc2 = fmaf(bf_lo(u11.y), w11, acc2);
    acc3 = fmaf(bf_hi(u11.y), w11, acc3);
  }

  ushort4 outv;
  __hip_bfloat16 h0 = __float2bfloat16(acc0);
  __hip_bfloat16 h1 = __float2bfloat16(acc1);
  __hip_bfloat16 h2 = __float2bfloat16(acc2);
  __hip_bfloat16 h3 = __float2bfloat16(acc3);
  outv.x = *(unsigned short*)&h0;
  outv.y = *(unsigned short*)&h1;
  outv.z = *(unsigned short*)&h2;
  outv.w = *(unsigned short*)&h3;
  *(ushort4*)(weighted + ((size_t)bq * HWH + pix) * 128 + n * 64 + lq4) = outv;
}

// ---------------- K4: 1x1 projection (K=128 GEMM) ----------------
__global__ __launch_bounds__(256) void proj_kernel(
    const __hip_bfloat16* __restrict__ weighted, const float* __restrict__ pwT,
    const float* __restrict__ pb, float* __restrict__ out) {
  __shared__ float A[64][129];
  int t = threadIdx.x;
  int pix0 = blockIdx.x * 64;

  const ushort4* src = reinterpret_cast<const ushort4*>(weighted + (size_t)pix0 * 128);
#pragma unroll
  for (int i = 0; i < 8; ++i) {
    int idx = i * 256 + t;
    ushort4 v = src[idx];
    int row = idx >> 5;
    int col = (idx & 31) * 4;
    A[row][col + 0] = __bfloat162float(*reinterpret_cast<__hip_bfloat16*>(&v.x));
    A[row][col + 1] = __bfloat162float(*reinterpret_cast<__hip_bfloat16*>(&v.y));
    A[row][col + 2] = __bfloat162float(*reinterpret_cast<__hip_bfloat16*>(&v.z));
    A[row][col + 3] = __bfloat162float(*reinterpret_cast<__hip_bfloat16*>(&v.w));
  }
  __syncthreads();

  int lane = t & 63;
  int g = __builtin_amdgcn_readfirstlane(t >> 6);

  float acc[32];
  const float* pbg = pb + g * 32;
#pragma unroll
  for (int j = 0; j < 32; ++j) acc[j] = pbg[j];

  const float* pwt_g = pwT + g * 32;
  for (int ci = 0; ci < 128; ++ci) {
    float a = A[lane][ci];
    const float* row = pwt_g + (size_t)ci * 128;
#pragma unroll
    for (int j = 0; j < 32; ++j) acc[j] = fmaf(a, row[j], acc[j]);
  }

  int gp = pix0 + lane;
  int b = gp / HWH;
  int pixl = gp % HWH;
  float* ob = out + ((size_t)b * CC + g * 32) * HWH + pixl;
#pragma unroll
  for (int j = 0; j < 32; ++j) ob[(size_t)j * HWH] = acc[j];
}

extern "C" void kernel_launch(void* const* d_in, const int* in_sizes, int n_in,
                              void* d_out, int out_size, void* d_ws, size_t ws_size,
                              hipStream_t stream) {
  const float* query = (const float*)d_in[0];
  const float* value = (const float*)d_in[1];
  const float* refp  = (const float*)d_in[2];
  const float* aw    = (const float*)d_in[3];
  const float* ab    = (const float*)d_in[4];
  const float* pw    = (const float*)d_in[5];
  const float* pb    = (const float*)d_in[6];
  float* out = (float*)d_out;

  // Workspace layout (aliased q_pad/weighted: q_pad dead after conv,
  // weighted first written by sample). Total 43,368,448 B.
  char* ws = (char*)d_ws;
  __hip_bfloat16* wtb      = (__hip_bfloat16*)(ws);             //   36864 B (pad 40960)
  float* pwT               = (float*)(ws + 40960);              //   65536 B
  float* attn_sm           = (float*)(ws + 106496);             // 4718592 B
  __hip_bfloat16* val_t    = (__hip_bfloat16*)(ws + 4825088);   // 18874368 B
  __hip_bfloat16* q_pad    = (__hip_bfloat16*)(ws + 23699456);  // 19668992 B (shared)
  __hip_bfloat16* weighted = (__hip_bfloat16*)(ws + 23699456);  // 18874368 B (shared)
  // end = 43368448 B

  hipMemsetAsync(q_pad, 0, (size_t)BB * PHW * 128 * 2, stream);
  prep_w_kernel<<<72, 256, 0, stream>>>(aw, pw, wtb, pwT);
  transpose_cl_kernel<<<4608, 256, 0, stream>>>(value, query, val_t, q_pad);
  attn_conv_mfma2<<<1152, 256, 0, stream>>>(q_pad, wtb, ab, attn_sm);
  sample_kernel<<<9216, 256, 0, stream>>>(val_t, attn_sm, refp, weighted);
  proj_kernel<<<(BB * HWH) / 64, 256, 0, stream>>>(weighted, pwT, pb, out);
}

// Round 8
// 234.685 us; speedup vs baseline: 2.3906x; 1.0948x over previous
//
#include <hip/hip_runtime.h>
#include <hip/hip_bf16.h>

#define BB 8
#define CC 128
#define HH 96
#define WW 96
#define HWH (HH*WW)   // 9216
#define NH 2
#define NP 8
#define PW 98         // padded width/height
#define PHW (PW*PW)   // 9604

typedef __attribute__((ext_vector_type(8))) short short8;
typedef __attribute__((ext_vector_type(4))) float f32x4;

__device__ __forceinline__ float bf_lo(unsigned u) { return __uint_as_float(u << 16); }
__device__ __forceinline__ float bf_hi(unsigned u) { return __uint_as_float(u & 0xffff0000u); }

// ---------------- K0: weight prep ----------------
// wtb[((k*16 + (c>>3))*16 + o)*8 + (c&7)] = bf16(aw[o][c][k])   (18432 bf16)
// pwb[co*128+ci] = bf16(pw[co][ci])                              (16384 bf16)
__global__ __launch_bounds__(256) void prep_w_kernel(
    const float* __restrict__ aw, const float* __restrict__ pw,
    __hip_bfloat16* __restrict__ wtb, __hip_bfloat16* __restrict__ pwb) {
  int t = blockIdx.x * 256 + threadIdx.x;
  for (int idx = t; idx < 9 * 16 * 16 * 8; idx += gridDim.x * 256) {
    int j = idx & 7;
    int o = (idx >> 3) & 15;
    int g = (idx >> 7) & 15;   // c>>3
    int k = idx >> 11;         // 0..8
    int c = g * 8 + j;
    wtb[idx] = __float2bfloat16(aw[o * 1152 + c * 9 + k]);
  }
  for (int idx = t; idx < 128 * 128; idx += gridDim.x * 256) {
    pwb[idx] = __float2bfloat16(pw[idx]);
  }
}

// ---------------- K1: transpose value AND query to channel-last bf16 ----------
__global__ __launch_bounds__(256) void transpose_cl_kernel(
    const float* __restrict__ value, const float* __restrict__ query,
    __hip_bfloat16* __restrict__ val_t, __hip_bfloat16* __restrict__ q_pad) {
  __shared__ float tile[64][65];
  int blk = blockIdx.x;
  int mode = blk / 2304;
  int r = blk % 2304;
  int ptile = r % 144;
  int bn = r / 144;
  int b = bn >> 1, n = bn & 1;
  int pix0 = ptile * 64;
  int t = threadIdx.x;
  int lane = t & 63;
  int row4 = t >> 6;

  const float* srcp = (mode ? query : value) + ((size_t)(b * CC + n * 64)) * HWH + pix0;
#pragma unroll
  for (int i = 0; i < 16; ++i) {
    int c = i * 4 + row4;
    tile[c][lane] = srcp[(size_t)c * HWH + lane];
  }
  __syncthreads();

  int d2 = t & 31;   // channel pair
  int ph = t >> 5;   // 0..7
  if (mode == 0) {
    __hip_bfloat16* dst = val_t + ((size_t)bn * HWH + pix0) * 64;
#pragma unroll
    for (int i = 0; i < 8; ++i) {
      int p = i * 8 + ph;
      __hip_bfloat162 v;
      v.x = __float2bfloat16(tile[d2 * 2][p]);
      v.y = __float2bfloat16(tile[d2 * 2 + 1][p]);
      *reinterpret_cast<__hip_bfloat162*>(dst + (size_t)p * 64 + d2 * 2) = v;
    }
  } else {
#pragma unroll
    for (int i = 0; i < 8; ++i) {
      int p = i * 8 + ph;
      int gp = pix0 + p;
      int h = gp / WW, w = gp - h * WW;
      __hip_bfloat162 v;
      v.x = __float2bfloat16(tile[d2 * 2][p]);
      v.y = __float2bfloat16(tile[d2 * 2 + 1][p]);
      size_t off = ((size_t)b * PHW + (size_t)(h + 1) * PW + (w + 1)) * 128 + n * 64 + d2 * 2;
      *reinterpret_cast<__hip_bfloat162*>(q_pad + off) = v;
    }
  }
}

// ---------------- K2: MFMA conv (128->16, 3x3) + softmax ----------------
__global__ __launch_bounds__(256) void attn_conv_mfma2(
    const __hip_bfloat16* __restrict__ q_pad, const __hip_bfloat16* __restrict__ wtb_,
    const float* __restrict__ bias, float* __restrict__ attn_out) {
  int t = threadIdx.x;
  int l = t & 63;
  int bid = blockIdx.x;
  int sbid = (bid & 7) * 144 + (bid >> 3);
  int tid = __builtin_amdgcn_readfirstlane(sbid * 4 + (t >> 6));  // 0..4607
  int b = tid / 576;
  int rem = tid % 576;
  int h = rem / 6;
  int w0 = (rem % 6) * 16;

  const char* qb = (const char*)q_pad;
  const char* wb = (const char*)wtb_;

  int pxbase = b * PHW + (h + 1) * PW + (w0 + 1);
  int lb  = (l & 15) * 256 + (l >> 4) * 16;   // A lane byte offset (px, ch-part)
  int wlb = (l >> 4) * 256 + (l & 15) * 16;   // B lane byte offset

  float bias_o = bias[l & 15];
  f32x4 acc0 = {bias_o, bias_o, bias_o, bias_o};
  f32x4 acc1 = {0.f, 0.f, 0.f, 0.f};

#pragma unroll
  for (int k = 0; k < 9; ++k) {
    int dy = k / 3 - 1, dx = (k % 3) - 1;
    const char* abase = qb + ((size_t)pxbase + dy * PW + dx) * 256 + lb;
    const char* bbase = wb + k * 4096 + wlb;
#pragma unroll
    for (int c4 = 0; c4 < 4; ++c4) {
      short8 a = *(const short8*)(abase + c4 * 64);
      short8 bf = *(const short8*)(bbase + c4 * 1024);
      if (k & 1)
        acc1 = __builtin_amdgcn_mfma_f32_16x16x32_bf16(a, bf, acc1, 0, 0, 0);
      else
        acc0 = __builtin_amdgcn_mfma_f32_16x16x32_bf16(a, bf, acc0, 0, 0, 0);
    }
  }

  int o = l & 15;
  size_t row0 = (size_t)b * HWH + (size_t)h * 96 + w0 + (l >> 4) * 4;
#pragma unroll
  for (int r = 0; r < 4; ++r) {
    float vv = acc0[r] + acc1[r];
    float mx = vv;
    mx = fmaxf(mx, __shfl_xor(mx, 1, 64));
    mx = fmaxf(mx, __shfl_xor(mx, 2, 64));
    mx = fmaxf(mx, __shfl_xor(mx, 4, 64));
    float e = __expf(vv - mx);
    float s = e;
    s += __shfl_xor(s, 1, 64);
    s += __shfl_xor(s, 2, 64);
    s += __shfl_xor(s, 4, 64);
    attn_out[(row0 + r) * 16 + o] = e / s;
  }
}

// ---------------- K3: bilinear sampling + point-weighted sum ----------------
__global__ __launch_bounds__(256) void sample_kernel(
    const __hip_bfloat16* __restrict__ val_t, const float* __restrict__ attn,
    const float* __restrict__ refp, __hip_bfloat16* __restrict__ weighted) {
  int t = threadIdx.x;
  int lane = t & 63;
  int sub = lane >> 4;          // pixel-unit within wave 0..3
  int lq = lane & 15;           // channel group (4 ch each)
  int bid = blockIdx.x;
  int sbid = (bid & 7) * 1152 + (bid >> 3);
  int unit = (sbid * 4 + (t >> 6)) * 4 + sub;   // 0..147455 = (b,n,pix)
  int bn = unit / HWH;
  int pix = unit - bn * HWH;
  int bq = bn >> 1, n = bn & 1;

  const float* ap = attn + ((size_t)bq * HWH + pix) * 16 + n * 8;
  const float* rp = refp + (((size_t)bq * HWH + pix) * NH + n) * 16;
  const __hip_bfloat16* vb = val_t + (size_t)bn * (HWH * 64);

  float4 a0 = *(const float4*)(ap);
  float4 a1 = *(const float4*)(ap + 4);
  float4 r0 = *(const float4*)(rp);
  float4 r1 = *(const float4*)(rp + 4);
  float4 r2 = *(const float4*)(rp + 8);
  float4 r3 = *(const float4*)(rp + 12);
  float aa[8] = {a0.x, a0.y, a0.z, a0.w, a1.x, a1.y, a1.z, a1.w};
  float rr[16] = {r0.x, r0.y, r0.z, r0.w, r1.x, r1.y, r1.z, r1.w,
                  r2.x, r2.y, r2.z, r2.w, r3.x, r3.y, r3.z, r3.w};

  float acc0 = 0.f, acc1 = 0.f, acc2 = 0.f, acc3 = 0.f;
  int lq4 = lq * 4;
#pragma unroll
  for (int p = 0; p < 8; ++p) {
    float a = aa[p];
    float x = rr[p * 2 + 0] * (float)WW - 0.5f;
    float y = rr[p * 2 + 1] * (float)HH - 0.5f;
    float x0f = floorf(x), y0f = floorf(y);
    float wx = x - x0f, wy = y - y0f;
    int x0 = (int)x0f, y0 = (int)y0f;

    float ay0 = a * (1.f - wy);  ay0 = (y0 >= 0)      ? ay0 : 0.f;
    float ay1 = a * wy;          ay1 = (y0 < HH - 1)  ? ay1 : 0.f;
    float bx0 = 1.f - wx;        bx0 = (x0 >= 0)      ? bx0 : 0.f;
    float bx1 = wx;              bx1 = (x0 < WW - 1)  ? bx1 : 0.f;

    int xc0 = max(x0, 0), xc1 = min(x0 + 1, WW - 1);
    int yc0 = max(y0, 0), yc1 = min(y0 + 1, HH - 1);

    int r0o = yc0 * (WW * 64);
    int r1o = yc1 * (WW * 64);
    int c0o = xc0 * 64 + lq4;
    int c1o = xc1 * 64 + lq4;

    uint2 u00 = *(const uint2*)(vb + (r0o + c0o));
    uint2 u01 = *(const uint2*)(vb + (r0o + c1o));
    uint2 u10 = *(const uint2*)(vb + (r1o + c0o));
    uint2 u11 = *(const uint2*)(vb + (r1o + c1o));

    float w00 = ay0 * bx0, w01 = ay0 * bx1, w10 = ay1 * bx0, w11 = ay1 * bx1;

    acc0 = fmaf(bf_lo(u00.x), w00, acc0);
    acc1 = fmaf(bf_hi(u00.x), w00, acc1);
    acc2 = fmaf(bf_lo(u00.y), w00, acc2);
    acc3 = fmaf(bf_hi(u00.y), w00, acc3);

    acc0 = fmaf(bf_lo(u01.x), w01, acc0);
    acc1 = fmaf(bf_hi(u01.x), w01, acc1);
    acc2 = fmaf(bf_lo(u01.y), w01, acc2);
    acc3 = fmaf(bf_hi(u01.y), w01, acc3);

    acc0 = fmaf(bf_lo(u10.x), w10, acc0);
    acc1 = fmaf(bf_hi(u10.x), w10, acc1);
    acc2 = fmaf(bf_lo(u10.y), w10, acc2);
    acc3 = fmaf(bf_hi(u10.y), w10, acc3);

    acc0 = fmaf(bf_lo(u11.x), w11, acc0);
    acc1 = fmaf(bf_hi(u11.x), w11, acc1);
    acc2 = fmaf(bf_lo(u11.y), w11, acc2);
    acc3 = fmaf(bf_hi(u11.y), w11, acc3);
  }

  ushort4 outv;
  __hip_bfloat16 h0 = __float2bfloat16(acc0);
  __hip_bfloat16 h1 = __float2bfloat16(acc1);
  __hip_bfloat16 h2 = __float2bfloat16(acc2);
  __hip_bfloat16 h3 = __float2bfloat16(acc3);
  outv.x = *(unsigned short*)&h0;
  outv.y = *(unsigned short*)&h1;
  outv.z = *(unsigned short*)&h2;
  outv.w = *(unsigned short*)&h3;
  *(ushort4*)(weighted + ((size_t)bq * HWH + pix) * 128 + n * 64 + lq4) = outv;
}

// ---------------- K4: 1x1 projection via MFMA ----------------
// Wave = 16 px x 128 co. A = pwb[co][ci] bf16, B = weighted[px][ci] bf16.
// D col (l&15) = px (N), D row ((l>>4)*4+r) = co-within-tile (M).
__global__ __launch_bounds__(256) void proj_mfma_kernel(
    const __hip_bfloat16* __restrict__ weighted, const __hip_bfloat16* __restrict__ pwb,
    const float* __restrict__ pb, float* __restrict__ out) {
  int t = threadIdx.x;
  int l = t & 63;
  int wv = t >> 6;
  int px0 = (blockIdx.x * 4 + wv) * 16;      // global pixel over B*HWH (tile of 16)
  int b = px0 / HWH;                          // uniform per wave (576 tiles per image)
  int pixl0 = px0 - b * HWH;

  const short* wgt = (const short*)pwb;
  const short* act = (const short*)weighted;

  // B-fragments: activations for the wave's 16 px, all 128 ci
  short8 bfrag[4];
#pragma unroll
  for (int kk = 0; kk < 4; ++kk)
    bfrag[kk] = *(const short8*)(act + ((size_t)(px0 + (l & 15)) << 7) + kk * 32 + (l >> 4) * 8);

  int arow = (l & 15) << 7;                   // A-operand row (co) byte base /2
  int kofs = (l >> 4) * 8;

  float* ob0 = out + (size_t)b * CC * HWH + pixl0 + (l & 15);
  int corow = (l >> 4) * 4;

#pragma unroll 2
  for (int ct = 0; ct < 8; ++ct) {
    float4 pb4 = *(const float4*)(pb + ct * 16 + corow);
    f32x4 acc = {pb4.x, pb4.y, pb4.z, pb4.w};
#pragma unroll
    for (int kk = 0; kk < 4; ++kk) {
      short8 afrag = *(const short8*)(wgt + ((ct * 16) << 7) + arow + kk * 32 + kofs);
      acc = __builtin_amdgcn_mfma_f32_16x16x32_bf16(afrag, bfrag[kk], acc, 0, 0, 0);
    }
    float* obc = ob0 + (size_t)(ct * 16 + corow) * HWH;
#pragma unroll
    for (int r = 0; r < 4; ++r)
      obc[(size_t)r * HWH] = acc[r];
  }
}

extern "C" void kernel_launch(void* const* d_in, const int* in_sizes, int n_in,
                              void* d_out, int out_size, void* d_ws, size_t ws_size,
                              hipStream_t stream) {
  const float* query = (const float*)d_in[0];
  const float* value = (const float*)d_in[1];
  const float* refp  = (const float*)d_in[2];
  const float* aw    = (const float*)d_in[3];
  const float* ab    = (const float*)d_in[4];
  const float* pw    = (const float*)d_in[5];
  const float* pb    = (const float*)d_in[6];
  float* out = (float*)d_out;

  // Workspace (q_pad/weighted aliased; total 43,335,680 B)
  char* ws = (char*)d_ws;
  __hip_bfloat16* wtb      = (__hip_bfloat16*)(ws);             //   36864 B (pad 40960)
  __hip_bfloat16* pwb      = (__hip_bfloat16*)(ws + 40960);     //   32768 B
  float* attn_sm           = (float*)(ws + 73728);              // 4718592 B
  __hip_bfloat16* val_t    = (__hip_bfloat16*)(ws + 4792320);   // 18874368 B
  __hip_bfloat16* q_pad    = (__hip_bfloat16*)(ws + 23666688);  // 19668992 B (shared)
  __hip_bfloat16* weighted = (__hip_bfloat16*)(ws + 23666688);  // 18874368 B (shared)
  // end = 43335680 B

  hipMemsetAsync(q_pad, 0, (size_t)BB * PHW * 128 * 2, stream);
  prep_w_kernel<<<72, 256, 0, stream>>>(aw, pw, wtb, pwb);
  transpose_cl_kernel<<<4608, 256, 0, stream>>>(value, query, val_t, q_pad);
  attn_conv_mfma2<<<1152, 256, 0, stream>>>(q_pad, wtb, ab, attn_sm);
  sample_kernel<<<9216, 256, 0, stream>>>(val_t, attn_sm, refp, weighted);
  proj_mfma_kernel<<<(BB * HWH) / 64, 256, 0, stream>>>(weighted, pwb, pb, out);
}

// Round 9
// 234.308 us; speedup vs baseline: 2.3944x; 1.0016x over previous
//
#include <hip/hip_runtime.h>
#include <hip/hip_bf16.h>

#define BB 8
#define CC 128
#define HH 96
#define WW 96
#define HWH (HH*WW)   // 9216
#define NH 2
#define NP 8
#define PW 98         // padded width/height
#define PHW (PW*PW)   // 9604

typedef __attribute__((ext_vector_type(8))) short short8;
typedef __attribute__((ext_vector_type(4))) float f32x4;
typedef __attribute__((ext_vector_type(2))) float f32x2;

__device__ __forceinline__ float bf_lo(unsigned u) { return __uint_as_float(u << 16); }
__device__ __forceinline__ float bf_hi(unsigned u) { return __uint_as_float(u & 0xffff0000u); }

// ---------------- K0: weight prep ----------------
// wtb[((k*16 + (c>>3))*16 + o)*8 + (c&7)] = bf16(aw[o][c][k])   (18432 bf16)
// pwb[co*128+ci] = bf16(pw[co][ci])                              (16384 bf16)
__global__ __launch_bounds__(256) void prep_w_kernel(
    const float* __restrict__ aw, const float* __restrict__ pw,
    __hip_bfloat16* __restrict__ wtb, __hip_bfloat16* __restrict__ pwb) {
  int t = blockIdx.x * 256 + threadIdx.x;
  for (int idx = t; idx < 9 * 16 * 16 * 8; idx += gridDim.x * 256) {
    int j = idx & 7;
    int o = (idx >> 3) & 15;
    int g = (idx >> 7) & 15;   // c>>3
    int k = idx >> 11;         // 0..8
    int c = g * 8 + j;
    wtb[idx] = __float2bfloat16(aw[o * 1152 + c * 9 + k]);
  }
  for (int idx = t; idx < 128 * 128; idx += gridDim.x * 256) {
    pwb[idx] = __float2bfloat16(pw[idx]);
  }
}

// ---------------- K1: transpose value AND query to channel-last bf16 ----------
__global__ __launch_bounds__(256) void transpose_cl_kernel(
    const float* __restrict__ value, const float* __restrict__ query,
    __hip_bfloat16* __restrict__ val_t, __hip_bfloat16* __restrict__ q_pad) {
  __shared__ float tile[64][65];
  int blk = blockIdx.x;
  int mode = blk / 2304;
  int r = blk % 2304;
  int ptile = r % 144;
  int bn = r / 144;
  int b = bn >> 1, n = bn & 1;
  int pix0 = ptile * 64;
  int t = threadIdx.x;
  int lane = t & 63;
  int row4 = t >> 6;

  const float* srcp = (mode ? query : value) + ((size_t)(b * CC + n * 64)) * HWH + pix0;
#pragma unroll
  for (int i = 0; i < 16; ++i) {
    int c = i * 4 + row4;
    tile[c][lane] = srcp[(size_t)c * HWH + lane];
  }
  __syncthreads();

  int d2 = t & 31;   // channel pair
  int ph = t >> 5;   // 0..7
  if (mode == 0) {
    __hip_bfloat16* dst = val_t + ((size_t)bn * HWH + pix0) * 64;
#pragma unroll
    for (int i = 0; i < 8; ++i) {
      int p = i * 8 + ph;
      __hip_bfloat162 v;
      v.x = __float2bfloat16(tile[d2 * 2][p]);
      v.y = __float2bfloat16(tile[d2 * 2 + 1][p]);
      *reinterpret_cast<__hip_bfloat162*>(dst + (size_t)p * 64 + d2 * 2) = v;
    }
  } else {
#pragma unroll
    for (int i = 0; i < 8; ++i) {
      int p = i * 8 + ph;
      int gp = pix0 + p;
      int h = gp / WW, w = gp - h * WW;
      __hip_bfloat162 v;
      v.x = __float2bfloat16(tile[d2 * 2][p]);
      v.y = __float2bfloat16(tile[d2 * 2 + 1][p]);
      size_t off = ((size_t)b * PHW + (size_t)(h + 1) * PW + (w + 1)) * 128 + n * 64 + d2 * 2;
      *reinterpret_cast<__hip_bfloat162*>(q_pad + off) = v;
    }
  }
}

// ---------------- K2: MFMA conv (128->16, 3x3) + softmax ----------------
__global__ __launch_bounds__(256) void attn_conv_mfma2(
    const __hip_bfloat16* __restrict__ q_pad, const __hip_bfloat16* __restrict__ wtb_,
    const float* __restrict__ bias, float* __restrict__ attn_out) {
  int t = threadIdx.x;
  int l = t & 63;
  int bid = blockIdx.x;
  int sbid = (bid & 7) * 144 + (bid >> 3);
  int tid = __builtin_amdgcn_readfirstlane(sbid * 4 + (t >> 6));  // 0..4607
  int b = tid / 576;
  int rem = tid % 576;
  int h = rem / 6;
  int w0 = (rem % 6) * 16;

  const char* qb = (const char*)q_pad;
  const char* wb = (const char*)wtb_;

  int pxbase = b * PHW + (h + 1) * PW + (w0 + 1);
  int lb  = (l & 15) * 256 + (l >> 4) * 16;   // A lane byte offset (px, ch-part)
  int wlb = (l >> 4) * 256 + (l & 15) * 16;   // B lane byte offset

  float bias_o = bias[l & 15];
  f32x4 acc0 = {bias_o, bias_o, bias_o, bias_o};
  f32x4 acc1 = {0.f, 0.f, 0.f, 0.f};

#pragma unroll
  for (int k = 0; k < 9; ++k) {
    int dy = k / 3 - 1, dx = (k % 3) - 1;
    const char* abase = qb + ((size_t)pxbase + dy * PW + dx) * 256 + lb;
    const char* bbase = wb + k * 4096 + wlb;
#pragma unroll
    for (int c4 = 0; c4 < 4; ++c4) {
      short8 a = *(const short8*)(abase + c4 * 64);
      short8 bf = *(const short8*)(bbase + c4 * 1024);
      if (k & 1)
        acc1 = __builtin_amdgcn_mfma_f32_16x16x32_bf16(a, bf, acc1, 0, 0, 0);
      else
        acc0 = __builtin_amdgcn_mfma_f32_16x16x32_bf16(a, bf, acc0, 0, 0, 0);
    }
  }

  int o = l & 15;
  size_t row0 = (size_t)b * HWH + (size_t)h * 96 + w0 + (l >> 4) * 4;
#pragma unroll
  for (int r = 0; r < 4; ++r) {
    float vv = acc0[r] + acc1[r];
    float mx = vv;
    mx = fmaxf(mx, __shfl_xor(mx, 1, 64));
    mx = fmaxf(mx, __shfl_xor(mx, 2, 64));
    mx = fmaxf(mx, __shfl_xor(mx, 4, 64));
    float e = __expf(vv - mx);
    float s = e;
    s += __shfl_xor(s, 1, 64);
    s += __shfl_xor(s, 2, 64);
    s += __shfl_xor(s, 4, 64);
    attn_out[(row0 + r) * 16 + o] = e / s;
  }
}

// ---------------- K3: FUSED sampling + projection ----------------
// Block = 64 px of one image. Phase 1: sample 128 (px,head) units into a
// 16 KB XOR-swizzled LDS tile (bf16 [px][128ci]). Phase 2: proj MFMA,
// B-frags from LDS, A-frags = pwb (L2-hot), out to NCHW f32.
// XCD swizzle: sbid = (bid&7)*144 + bid>>3 -> XCD k owns batch k.
__global__ __launch_bounds__(256) void fused_sp_kernel(
    const __hip_bfloat16* __restrict__ val_t, const float* __restrict__ attn,
    const float* __restrict__ refp, const __hip_bfloat16* __restrict__ pwb,
    const float* __restrict__ pb, float* __restrict__ out) {
  __shared__ char lds[16384];
  int t = threadIdx.x;
  int l = t & 63;
  int wv = t >> 6;
  int sub = l >> 4;            // unit-slot within wave
  int lq = l & 15;             // channel quad (4 ch)
  int lq8 = lq * 8;            // byte offset of quad within 256-B ci row

  int bid = blockIdx.x;
  int sbid = (bid & 7) * 144 + (bid >> 3);    // 1152 blocks, XCD-chunked
  int b = sbid / 144;
  int px0l = (sbid % 144) * 64;               // pixel base within image
  size_t gpx0 = (size_t)b * HWH + px0l;

  // ---------- Phase 1: sampling into LDS ----------
#pragma unroll 2
  for (int i = 0; i < 8; ++i) {
    int u = i * 16 + wv * 4 + sub;            // 0..127
    int n = u & 1;
    int pxl = u >> 1;                         // 0..63
    int pix = px0l + pxl;

    const float* ap = attn + (gpx0 + pxl) * 16 + n * 8;
    const float* rp = refp + ((gpx0 + pxl) * NH + n) * 16;
    const __hip_bfloat16* vb = val_t + (size_t)(b * 2 + n) * (HWH * 64);

    float4 a0 = *(const float4*)(ap);
    float4 a1 = *(const float4*)(ap + 4);
    float4 r0 = *(const float4*)(rp);
    float4 r1 = *(const float4*)(rp + 4);
    float4 r2 = *(const float4*)(rp + 8);
    float4 r3 = *(const float4*)(rp + 12);
    float aa[8] = {a0.x, a0.y, a0.z, a0.w, a1.x, a1.y, a1.z, a1.w};
    float rr[16] = {r0.x, r0.y, r0.z, r0.w, r1.x, r1.y, r1.z, r1.w,
                    r2.x, r2.y, r2.z, r2.w, r3.x, r3.y, r3.z, r3.w};

    f32x2 acc01 = {0.f, 0.f}, acc23 = {0.f, 0.f};
    int lq4 = lq * 4;
#pragma unroll
    for (int p = 0; p < 8; ++p) {
      float a = aa[p];
      float x = rr[p * 2 + 0] * (float)WW - 0.5f;
      float y = rr[p * 2 + 1] * (float)HH - 0.5f;
      float x0f = floorf(x), y0f = floorf(y);
      float wx = x - x0f, wy = y - y0f;
      int x0 = (int)x0f, y0 = (int)y0f;

      float ay0 = a * (1.f - wy);  ay0 = (y0 >= 0)      ? ay0 : 0.f;
      float ay1 = a * wy;          ay1 = (y0 < HH - 1)  ? ay1 : 0.f;
      float bx0 = 1.f - wx;        bx0 = (x0 >= 0)      ? bx0 : 0.f;
      float bx1 = wx;              bx1 = (x0 < WW - 1)  ? bx1 : 0.f;

      int xc0 = max(x0, 0), xc1 = min(x0 + 1, WW - 1);
      int yc0 = max(y0, 0), yc1 = min(y0 + 1, HH - 1);

      int r0o = yc0 * (WW * 64);
      int r1o = yc1 * (WW * 64);
      int c0o = xc0 * 64 + lq4;
      int c1o = xc1 * 64 + lq4;

      uint2 u00 = *(const uint2*)(vb + (r0o + c0o));
      uint2 u01 = *(const uint2*)(vb + (r0o + c1o));
      uint2 u10 = *(const uint2*)(vb + (r1o + c0o));
      uint2 u11 = *(const uint2*)(vb + (r1o + c1o));

      float w00 = ay0 * bx0, w01 = ay0 * bx1, w10 = ay1 * bx0, w11 = ay1 * bx1;

      f32x2 wv2;
      wv2 = (f32x2){w00, w00};
      acc01 = __builtin_elementwise_fma((f32x2){bf_lo(u00.x), bf_hi(u00.x)}, wv2, acc01);
      acc23 = __builtin_elementwise_fma((f32x2){bf_lo(u00.y), bf_hi(u00.y)}, wv2, acc23);
      wv2 = (f32x2){w01, w01};
      acc01 = __builtin_elementwise_fma((f32x2){bf_lo(u01.x), bf_hi(u01.x)}, wv2, acc01);
      acc23 = __builtin_elementwise_fma((f32x2){bf_lo(u01.y), bf_hi(u01.y)}, wv2, acc23);
      wv2 = (f32x2){w10, w10};
      acc01 = __builtin_elementwise_fma((f32x2){bf_lo(u10.x), bf_hi(u10.x)}, wv2, acc01);
      acc23 = __builtin_elementwise_fma((f32x2){bf_lo(u10.y), bf_hi(u10.y)}, wv2, acc23);
      wv2 = (f32x2){w11, w11};
      acc01 = __builtin_elementwise_fma((f32x2){bf_lo(u11.x), bf_hi(u11.x)}, wv2, acc01);
      acc23 = __builtin_elementwise_fma((f32x2){bf_lo(u11.y), bf_hi(u11.y)}, wv2, acc23);
    }

    ushort4 outv;
    __hip_bfloat16 h0 = __float2bfloat16(acc01.x);
    __hip_bfloat16 h1 = __float2bfloat16(acc01.y);
    __hip_bfloat16 h2 = __float2bfloat16(acc23.x);
    __hip_bfloat16 h3 = __float2bfloat16(acc23.y);
    outv.x = *(unsigned short*)&h0;
    outv.y = *(unsigned short*)&h1;
    outv.z = *(unsigned short*)&h2;
    outv.w = *(unsigned short*)&h3;
    int byte = pxl * 256 + n * 128 + lq8;
    byte ^= (pxl & 7) << 4;                   // swizzle (bits 4-6)
    *(ushort4*)(&lds[byte]) = outv;
  }
  __syncthreads();

  // ---------- Phase 2: projection MFMA (wave = 16 px x 128 co) ----------
  int pxl_r = wv * 16 + (l & 15);
  const short* wgt = (const short*)pwb;

  short8 bfrag[4];
#pragma unroll
  for (int kk = 0; kk < 4; ++kk) {
    int byte = pxl_r * 256 + kk * 64 + (l >> 4) * 16;
    byte ^= (pxl_r & 7) << 4;
    bfrag[kk] = *(const short8*)(&lds[byte]);
  }

  int arow = (l & 15) << 7;
  int kofs = (l >> 4) * 8;
  int corow = (l >> 4) * 4;
  float* ob0 = out + (size_t)b * CC * HWH + (px0l + wv * 16) + (l & 15);

#pragma unroll 2
  for (int ct = 0; ct < 8; ++ct) {
    float4 pb4 = *(const float4*)(pb + ct * 16 + corow);
    f32x4 acc = {pb4.x, pb4.y, pb4.z, pb4.w};
#pragma unroll
    for (int kk = 0; kk < 4; ++kk) {
      short8 afrag = *(const short8*)(wgt + ((ct * 16) << 7) + arow + kk * 32 + kofs);
      acc = __builtin_amdgcn_mfma_f32_16x16x32_bf16(afrag, bfrag[kk], acc, 0, 0, 0);
    }
    float* obc = ob0 + (size_t)(ct * 16 + corow) * HWH;
#pragma unroll
    for (int r = 0; r < 4; ++r)
      obc[(size_t)r * HWH] = acc[r];
  }
}

extern "C" void kernel_launch(void* const* d_in, const int* in_sizes, int n_in,
                              void* d_out, int out_size, void* d_ws, size_t ws_size,
                              hipStream_t stream) {
  const float* query = (const float*)d_in[0];
  const float* value = (const float*)d_in[1];
  const float* refp  = (const float*)d_in[2];
  const float* aw    = (const float*)d_in[3];
  const float* ab    = (const float*)d_in[4];
  const float* pw    = (const float*)d_in[5];
  const float* pb    = (const float*)d_in[6];
  float* out = (float*)d_out;

  // Workspace: total 43,335,680 B (no weighted buffer anymore)
  char* ws = (char*)d_ws;
  __hip_bfloat16* wtb   = (__hip_bfloat16*)(ws);              //   36864 B (pad 40960)
  __hip_bfloat16* pwb   = (__hip_bfloat16*)(ws + 40960);      //   32768 B
  float* attn_sm        = (float*)(ws + 73728);               // 4718592 B
  __hip_bfloat16* val_t = (__hip_bfloat16*)(ws + 4792320);    // 18874368 B
  __hip_bfloat16* q_pad = (__hip_bfloat16*)(ws + 23666688);   // 19668992 B
  // end = 43335680 B

  hipMemsetAsync(q_pad, 0, (size_t)BB * PHW * 128 * 2, stream);
  prep_w_kernel<<<72, 256, 0, stream>>>(aw, pw, wtb, pwb);
  transpose_cl_kernel<<<4608, 256, 0, stream>>>(value, query, val_t, q_pad);
  attn_conv_mfma2<<<1152, 256, 0, stream>>>(q_pad, wtb, ab, attn_sm);
  fused_sp_kernel<<<1152, 256, 0, stream>>>(val_t, attn_sm, refp, pwb, pb, out);
}